// Round 1
// baseline (1250.098 us; speedup 1.0000x reference)
//
#include <hip/hip_runtime.h>
#include <math.h>

#define N_NODES 100000
#define N_EDGES 3200000
#define F_IN    37
#define H_DIM   16
#define C_DIM   2

// ---------------- degree: deg[col[e]] += w[e] ----------------
__global__ void k_degree(const int* __restrict__ col, const float* __restrict__ w,
                         float* __restrict__ deg) {
    int e = blockIdx.x * blockDim.x + threadIdx.x;
    if (e < N_EDGES) atomicAdd(&deg[col[e]], w[e]);
}

// ---------------- dinv in place: dinv = rsqrt(deg + 1) ----------------
__global__ void k_dinv(float* __restrict__ deg_dinv) {
    int i = blockIdx.x * blockDim.x + threadIdx.x;
    if (i < N_NODES) {
        float d = deg_dinv[i] + 1.0f;           // + self-loop weight 1.0
        deg_dinv[i] = (d > 0.f) ? rsqrtf(d) : 0.f;
    }
}

// ---------------- norm[e] = dinv[row]*w*dinv[col] ----------------
__global__ void k_norm(const int* __restrict__ row, const int* __restrict__ col,
                       const float* __restrict__ w, const float* __restrict__ dinv,
                       float* __restrict__ norm) {
    int e = blockIdx.x * blockDim.x + threadIdx.x;
    if (e < N_EDGES) norm[e] = dinv[row[e]] * w[e] * dinv[col[e]];
}

// ---------------- h1 = x @ W1  (N x 37) @ (37 x 16) ----------------
__global__ void k_xw1(const float* __restrict__ x, const float* __restrict__ W1,
                      float* __restrict__ h1) {
    __shared__ float sW[F_IN * H_DIM];
    for (int t = threadIdx.x; t < F_IN * H_DIM; t += blockDim.x) sW[t] = W1[t];
    __syncthreads();
    int i = blockIdx.x * blockDim.x + threadIdx.x;
    if (i >= N_NODES) return;
    float acc[H_DIM];
#pragma unroll
    for (int j = 0; j < H_DIM; j++) acc[j] = 0.f;
    const float* xi = x + (size_t)i * F_IN;
    for (int k = 0; k < F_IN; k++) {
        float xv = xi[k];
#pragma unroll
        for (int j = 0; j < H_DIM; j++) acc[j] += xv * sW[k * H_DIM + j];
    }
    float* out = h1 + (size_t)i * H_DIM;
#pragma unroll
    for (int j = 0; j < H_DIM; j++) out[j] = acc[j];
}

// ---------------- agg1: out1[col] += norm * h1[row]  (16 feats, 4 thr/edge) ----------------
__global__ void k_agg1(const int* __restrict__ row, const int* __restrict__ col,
                       const float* __restrict__ norm, const float* __restrict__ h1,
                       float* __restrict__ out1) {
    int id = blockIdx.x * blockDim.x + threadIdx.x;
    int e = id >> 2, q = id & 3;
    if (e >= N_EDGES) return;
    int r = row[e], c = col[e];
    float nv = norm[e];
    float4 hv = ((const float4*)h1)[(size_t)r * 4 + q];
    float* dst = out1 + (size_t)c * H_DIM + q * 4;
    atomicAdd(dst + 0, nv * hv.x);
    atomicAdd(dst + 1, nv * hv.y);
    atomicAdd(dst + 2, nv * hv.z);
    atomicAdd(dst + 3, nv * hv.w);
}

// ---------------- layer1 epilogue + layer2 dense:
// h = relu(out1 + selfnorm*h1 + b1);  h2 = h @ W2 ----------------
__global__ void k_post1(const float* __restrict__ out1, const float* __restrict__ h1,
                        const float* __restrict__ dinv, const float* __restrict__ b1,
                        const float* __restrict__ W2, float* __restrict__ h2) {
    __shared__ float sW[H_DIM * C_DIM];
    __shared__ float sb[H_DIM];
    if (threadIdx.x < H_DIM * C_DIM) sW[threadIdx.x] = W2[threadIdx.x];
    if (threadIdx.x < H_DIM) sb[threadIdx.x] = b1[threadIdx.x];
    __syncthreads();
    int i = blockIdx.x * blockDim.x + threadIdx.x;
    if (i >= N_NODES) return;
    float di = dinv[i];
    float sn = di * di;                 // self-loop norm = dinv^2 (w=1)
    float a0 = 0.f, a1 = 0.f;
    const float* o = out1 + (size_t)i * H_DIM;
    const float* h = h1 + (size_t)i * H_DIM;
#pragma unroll
    for (int j = 0; j < H_DIM; j++) {
        float v = o[j] + sn * h[j] + sb[j];
        v = v > 0.f ? v : 0.f;
        a0 += v * sW[j * C_DIM + 0];
        a1 += v * sW[j * C_DIM + 1];
    }
    h2[(size_t)i * C_DIM + 0] = a0;
    h2[(size_t)i * C_DIM + 1] = a1;
}

// ---------------- agg2: out2[col] += norm * h2[row]  (2 feats) ----------------
__global__ void k_agg2(const int* __restrict__ row, const int* __restrict__ col,
                       const float* __restrict__ norm, const float* __restrict__ h2,
                       float* __restrict__ out2) {
    int e = blockIdx.x * blockDim.x + threadIdx.x;
    if (e >= N_EDGES) return;
    int r = row[e], c = col[e];
    float nv = norm[e];
    float2 hv = ((const float2*)h2)[r];
    atomicAdd(&out2[(size_t)c * C_DIM + 0], nv * hv.x);
    atomicAdd(&out2[(size_t)c * C_DIM + 1], nv * hv.y);
}

// ---------------- final: logits = out2 + selfnorm*h2 + b2; log_softmax ----------------
__global__ void k_final(const float* __restrict__ out2, const float* __restrict__ h2,
                        const float* __restrict__ dinv, const float* __restrict__ b2,
                        float* __restrict__ out) {
    int i = blockIdx.x * blockDim.x + threadIdx.x;
    if (i >= N_NODES) return;
    float di = dinv[i];
    float sn = di * di;
    float l0 = out2[(size_t)i * 2 + 0] + sn * h2[(size_t)i * 2 + 0] + b2[0];
    float l1 = out2[(size_t)i * 2 + 1] + sn * h2[(size_t)i * 2 + 1] + b2[1];
    float m = fmaxf(l0, l1);
    float lse = m + logf(expf(l0 - m) + expf(l1 - m));
    out[(size_t)i * 2 + 0] = l0 - lse;
    out[(size_t)i * 2 + 1] = l1 - lse;
}

extern "C" void kernel_launch(void* const* d_in, const int* in_sizes, int n_in,
                              void* d_out, int out_size, void* d_ws, size_t ws_size,
                              hipStream_t stream) {
    const float* x  = (const float*)d_in[0];
    const int*   ei = (const int*)d_in[1];     // [2, E] row-major: row then col
    const float* w  = (const float*)d_in[2];
    const float* W1 = (const float*)d_in[3];
    const float* b1 = (const float*)d_in[4];
    const float* W2 = (const float*)d_in[5];
    const float* b2 = (const float*)d_in[6];
    float* out = (float*)d_out;

    const int* row = ei;
    const int* col = ei + N_EDGES;

    // workspace layout (all offsets multiple of 16 bytes)
    char* ws = (char*)d_ws;
    float* deg_dinv = (float*)(ws + 0);                     //   400,000 B
    float* out1     = (float*)(ws + 400000);                // 6,400,000 B
    float* out2     = (float*)(ws + 6800000);               //   800,000 B
    float* norm     = (float*)(ws + 7600000);               //12,800,000 B
    float* h1       = (float*)(ws + 20400000);              // 6,400,000 B
    float* h2       = (float*)(ws + 26800000);              //   800,000 B
    // total 27,600,000 B

    // zero the accumulators (deg, out1, out2 are contiguous at offset 0)
    hipMemsetAsync(d_ws, 0, 7600000, stream);

    const int B = 256;
    const int gE = (N_EDGES + B - 1) / B;       // 12500
    const int gN = (N_NODES + B - 1) / B;       // 391

    k_degree<<<gE, B, 0, stream>>>(col, w, deg_dinv);
    k_dinv  <<<gN, B, 0, stream>>>(deg_dinv);
    k_norm  <<<gE, B, 0, stream>>>(row, col, w, deg_dinv, norm);
    k_xw1   <<<gN, B, 0, stream>>>(x, W1, h1);
    k_agg1  <<<(N_EDGES * 4 + B - 1) / B, B, 0, stream>>>(row, col, norm, h1, out1);
    k_post1 <<<gN, B, 0, stream>>>(out1, h1, deg_dinv, b1, W2, h2);
    k_agg2  <<<gE, B, 0, stream>>>(row, col, norm, h2, out2);
    k_final <<<gN, B, 0, stream>>>(out2, h2, deg_dinv, b2, out);
}

// Round 2
// 627.340 us; speedup vs baseline: 1.9927x; 1.9927x over previous
//
#include <hip/hip_runtime.h>
#include <math.h>

#define N_NODES 100000
#define N_EDGES 3200000
#define F_IN    37
#define H_DIM   16
#define C_DIM   2
#define NBLK    391          // ceil(N_NODES/256)

// ---------- CSR build: histogram of destination (col) ----------
__global__ void k_hist(const int* __restrict__ col, int* __restrict__ hist) {
    int e = blockIdx.x * blockDim.x + threadIdx.x;
    if (e < N_EDGES) atomicAdd(&hist[col[e]], 1);
}

// ---------- scan pass 1: per-block exclusive scan, emit block sums ----------
__global__ void k_scan1(const int* __restrict__ hist, int* __restrict__ rowptr,
                        int* __restrict__ bsum) {
    __shared__ int s[256];
    int t = threadIdx.x;
    int i = blockIdx.x * 256 + t;
    int v = (i < N_NODES) ? hist[i] : 0;
    s[t] = v;
    __syncthreads();
    for (int off = 1; off < 256; off <<= 1) {
        int tmp = (t >= off) ? s[t - off] : 0;
        __syncthreads();
        s[t] += tmp;
        __syncthreads();
    }
    if (i < N_NODES) rowptr[i] = s[t] - v;     // exclusive within block
    if (t == 255) bsum[blockIdx.x] = s[255];
}

// ---------- scan pass 2: scan the 391 block sums (single block) ----------
__global__ void k_scan2(int* __restrict__ bsum) {
    __shared__ int s[512];
    int t = threadIdx.x;
    int v = (t < NBLK) ? bsum[t] : 0;
    s[t] = v;
    __syncthreads();
    for (int off = 1; off < 512; off <<= 1) {
        int tmp = (t >= off) ? s[t - off] : 0;
        __syncthreads();
        s[t] += tmp;
        __syncthreads();
    }
    if (t < NBLK) bsum[t] = s[t] - v;          // exclusive
}

// ---------- scan pass 3: add block offsets; init cursor = rowptr ----------
__global__ void k_scan3(int* __restrict__ rowptr, const int* __restrict__ bsum,
                        int* __restrict__ cursor) {
    int t = threadIdx.x;
    int i = blockIdx.x * 256 + t;
    if (i < N_NODES) {
        int rp = rowptr[i] + bsum[blockIdx.x];
        rowptr[i] = rp;
        cursor[i] = rp;
    }
    if (blockIdx.x == 0 && t == 0) rowptr[N_NODES] = N_EDGES;
}

// ---------- scatter edges into CSR order: pack = (row, w) ----------
__global__ void k_scatter(const int* __restrict__ row, const int* __restrict__ col,
                          const float* __restrict__ w, int* __restrict__ cursor,
                          int2* __restrict__ pack) {
    int e = blockIdx.x * blockDim.x + threadIdx.x;
    if (e >= N_EDGES) return;
    int c = col[e];
    int p = atomicAdd(&cursor[c], 1);
    pack[p] = make_int2(row[e], __float_as_int(w[e]));
}

// ---------- dinv[i] = rsqrt(1 + sum_w over segment) ----------
__global__ void k_dinv(const int* __restrict__ rowptr, const int2* __restrict__ pack,
                       float* __restrict__ dinv) {
    int i = blockIdx.x * blockDim.x + threadIdx.x;
    if (i >= N_NODES) return;
    int s = rowptr[i], e = rowptr[i + 1];
    float sum = 1.0f;                     // self-loop weight
    for (int p = s; p < e; p++) sum += __int_as_float(pack[p].y);
    dinv[i] = rsqrtf(sum);
}

// ---------- fold a = dinv[row] * w into pack.y ----------
__global__ void k_scale(int2* __restrict__ pack, const float* __restrict__ dinv) {
    int p = blockIdx.x * blockDim.x + threadIdx.x;
    if (p >= N_EDGES) return;
    int2 v = pack[p];
    v.y = __float_as_int(dinv[v.x] * __int_as_float(v.y));
    pack[p] = v;
}

// ---------- h1 = x @ W1 ----------
__global__ void k_xw1(const float* __restrict__ x, const float* __restrict__ W1,
                      float* __restrict__ h1) {
    __shared__ float sW[F_IN * H_DIM];
    for (int t = threadIdx.x; t < F_IN * H_DIM; t += blockDim.x) sW[t] = W1[t];
    __syncthreads();
    int i = blockIdx.x * blockDim.x + threadIdx.x;
    if (i >= N_NODES) return;
    float acc[H_DIM];
#pragma unroll
    for (int j = 0; j < H_DIM; j++) acc[j] = 0.f;
    const float* xi = x + (size_t)i * F_IN;
    for (int k = 0; k < F_IN; k++) {
        float xv = xi[k];
#pragma unroll
        for (int j = 0; j < H_DIM; j++) acc[j] += xv * sW[k * H_DIM + j];
    }
    float* o = h1 + (size_t)i * H_DIM;
#pragma unroll
    for (int j = 0; j < H_DIM; j++) o[j] = acc[j];
}

// ---------- layer 1 aggregate (atomic-free): 4 threads/node, float4 each ----------
// h_relu[c] = relu(dinv_c * sum_e(a_e * h1[r_e]) + dinv_c^2 * h1[c] + b1)
__global__ void k_agg1(const int* __restrict__ rowptr, const int2* __restrict__ pack,
                       const float* __restrict__ h1, const float* __restrict__ dinv,
                       const float* __restrict__ b1, float* __restrict__ h_relu) {
    int id = blockIdx.x * blockDim.x + threadIdx.x;
    int c = id >> 2, q = id & 3;
    if (c >= N_NODES) return;
    int s = rowptr[c], e = rowptr[c + 1];
    const float4* h14 = (const float4*)h1;
    float4 acc = make_float4(0.f, 0.f, 0.f, 0.f);
    for (int p = s; p < e; p++) {
        int2 v = pack[p];
        float a = __int_as_float(v.y);
        float4 hv = h14[(size_t)v.x * 4 + q];
        acc.x += a * hv.x; acc.y += a * hv.y;
        acc.z += a * hv.z; acc.w += a * hv.w;
    }
    float dc = dinv[c];
    float sn = dc * dc;
    float4 hc = h14[(size_t)c * 4 + q];
    float4 bq = ((const float4*)b1)[q];
    float4 r;
    r.x = fmaxf(dc * acc.x + sn * hc.x + bq.x, 0.f);
    r.y = fmaxf(dc * acc.y + sn * hc.y + bq.y, 0.f);
    r.z = fmaxf(dc * acc.z + sn * hc.z + bq.z, 0.f);
    r.w = fmaxf(dc * acc.w + sn * hc.w + bq.w, 0.f);
    ((float4*)h_relu)[(size_t)c * 4 + q] = r;
}

// ---------- h2 = h_relu @ W2 ----------
__global__ void k_h2(const float* __restrict__ h_relu, const float* __restrict__ W2,
                     float* __restrict__ h2) {
    __shared__ float sW[H_DIM * C_DIM];
    if (threadIdx.x < H_DIM * C_DIM) sW[threadIdx.x] = W2[threadIdx.x];
    __syncthreads();
    int i = blockIdx.x * blockDim.x + threadIdx.x;
    if (i >= N_NODES) return;
    const float* h = h_relu + (size_t)i * H_DIM;
    float a0 = 0.f, a1 = 0.f;
#pragma unroll
    for (int j = 0; j < H_DIM; j++) {
        float v = h[j];
        a0 += v * sW[j * C_DIM + 0];
        a1 += v * sW[j * C_DIM + 1];
    }
    ((float2*)h2)[i] = make_float2(a0, a1);
}

// ---------- layer 2 aggregate + bias + log_softmax (atomic-free) ----------
__global__ void k_agg2(const int* __restrict__ rowptr, const int2* __restrict__ pack,
                       const float* __restrict__ h2, const float* __restrict__ dinv,
                       const float* __restrict__ b2, float* __restrict__ out) {
    int c = blockIdx.x * blockDim.x + threadIdx.x;
    if (c >= N_NODES) return;
    int s = rowptr[c], e = rowptr[c + 1];
    const float2* h22 = (const float2*)h2;
    float a0 = 0.f, a1 = 0.f;
    for (int p = s; p < e; p++) {
        int2 v = pack[p];
        float a = __int_as_float(v.y);
        float2 hv = h22[v.x];
        a0 += a * hv.x;
        a1 += a * hv.y;
    }
    float dc = dinv[c];
    float sn = dc * dc;
    float2 hc = h22[c];
    float l0 = dc * a0 + sn * hc.x + b2[0];
    float l1 = dc * a1 + sn * hc.y + b2[1];
    float m = fmaxf(l0, l1);
    float lse = m + logf(expf(l0 - m) + expf(l1 - m));
    ((float2*)out)[c] = make_float2(l0 - lse, l1 - lse);
}

extern "C" void kernel_launch(void* const* d_in, const int* in_sizes, int n_in,
                              void* d_out, int out_size, void* d_ws, size_t ws_size,
                              hipStream_t stream) {
    const float* x  = (const float*)d_in[0];
    const int*   ei = (const int*)d_in[1];     // [2, E]: row then col
    const float* w  = (const float*)d_in[2];
    const float* W1 = (const float*)d_in[3];
    const float* b1 = (const float*)d_in[4];
    const float* W2 = (const float*)d_in[5];
    const float* b2 = (const float*)d_in[6];
    float* out = (float*)d_out;

    const int* row = ei;
    const int* col = ei + N_EDGES;

    // workspace layout (16B-aligned offsets), total ~40.4 MB
    char* ws = (char*)d_ws;
    int*   hist_cur = (int*)(ws + 0);            //   400,000 B (hist, then cursor)
    int*   rowptr   = (int*)(ws + 400000);       //   400,016 B (N+1 ints)
    int*   bsum     = (int*)(ws + 800016);       //     2,048 B
    int2*  pack     = (int2*)(ws + 802064);      //25,600,000 B
    float* dinv     = (float*)(ws + 26402064);   //   400,000 B
    float* h1       = (float*)(ws + 26802064);   // 6,400,000 B
    float* h_relu   = (float*)(ws + 33202064);   // 6,400,000 B
    float* h2       = (float*)(ws + 39602064);   //   800,000 B
    // end: 40,402,064 B

    hipMemsetAsync(hist_cur, 0, 400000, stream);   // zero histogram only

    const int B  = 256;
    const int gE = (N_EDGES + B - 1) / B;          // 12500
    const int gN = (N_NODES + B - 1) / B;          // 391
    const int g4N = (4 * N_NODES + B - 1) / B;     // 1563

    k_hist   <<<gE, B, 0, stream>>>(col, hist_cur);
    k_scan1  <<<NBLK, B, 0, stream>>>(hist_cur, rowptr, bsum);
    k_scan2  <<<1, 512, 0, stream>>>(bsum);
    k_scan3  <<<NBLK, B, 0, stream>>>(rowptr, bsum, hist_cur);
    k_scatter<<<gE, B, 0, stream>>>(row, col, w, hist_cur, pack);
    k_dinv   <<<gN, B, 0, stream>>>(rowptr, pack, dinv);
    k_scale  <<<gE, B, 0, stream>>>(pack, dinv);
    k_xw1    <<<gN, B, 0, stream>>>(x, W1, h1);
    k_agg1   <<<g4N, B, 0, stream>>>(rowptr, pack, h1, dinv, b1, h_relu);
    k_h2     <<<gN, B, 0, stream>>>(h_relu, W2, h2);
    k_agg2   <<<gN, B, 0, stream>>>(rowptr, pack, h2, dinv, b2, out);
}